// Round 6
// baseline (69.167 us; speedup 1.0000x reference)
//
#include <hip/hip_runtime.h>

// CARAFE upsample: B=2, C=256, H=W=64, S=2, K=5, COMP=64, KP=100
// prep -> encoder (1x1, fp16-pair out) -> kp conv (3x3 fp16 dot2, s_load weights,
//         fused softmax) -> gather (fp16 dot2)

#define NB 2
#define NC 256

typedef _Float16 h2v __attribute__((ext_vector_type(2)));
typedef __fp16 f16x2 __attribute__((ext_vector_type(2)));
union U32H2 { unsigned u; h2v h; f16x2 f; };
static __device__ __forceinline__ h2v u2h(unsigned u) { U32H2 t; t.u = u; return t.h; }
static __device__ __forceinline__ unsigned pkh(float a, float b) {
    U32H2 t; t.f = __builtin_amdgcn_cvt_pkrtz(a, b); return t.u;
}

// ---------------- prep: whr[g][cp32][d9][k2 pad28] fp16-pairs + wt[half][c][o32] ----------------
__global__ __launch_bounds__(256) void prep_weights(const float* __restrict__ w_kp,
        const float* __restrict__ w_enc, unsigned* __restrict__ whr, float* __restrict__ wt) {
    int idx = blockIdx.x * 256 + threadIdx.x;
    if (idx < 32256) {
        int k = idx % 28;
        int d = (idx / 28) % 9;
        int cp = (idx / 252) % 32;
        int g = idx / 8064;
        unsigned val = 0;
        if (k < 25) {
            float a = w_kp[((size_t)(k * 4 + g) * 64 + 2 * cp) * 9 + d];
            float b = w_kp[((size_t)(k * 4 + g) * 64 + 2 * cp + 1) * 9 + d];
            val = pkh(a, b);
        }
        whr[idx] = val;
    }
    int j = idx - 32256;
    if (j >= 0 && j < 16384) {
        int o32 = j % 32;
        int c = (j / 32) % 256;
        int half = j / 8192;
        wt[j] = w_enc[(half * 32 + o32) * 256 + c];
    }
}

// ---------------- A: encoder -> xch[b][cp32][px4096] fp16 pairs ----------------
// grid 256: (b, h, half); 512 thr = 8 waves; wave og -> 4 outputs; x row staged in LDS
__global__ __launch_bounds__(512) void encoder_kernel(const float* __restrict__ x,
        const float* __restrict__ wt, const float* __restrict__ b_enc,
        unsigned* __restrict__ xch) {
    __shared__ float xs[256 * 64];   // 64 KB
    int bid = blockIdx.x;
    int half = bid & 1;
    int h = (bid >> 1) & 63;
    int b = bid >> 7;
    int tid = threadIdx.x;
    for (int i = 0; i < 32; ++i) {
        int f = i * 512 + tid;
        int c = f >> 6, w = f & 63;
        xs[f] = x[((size_t)(b * NC + c)) * 4096 + h * 64 + w];
    }
    __syncthreads();
    int wl = tid & 63;
    int og = __builtin_amdgcn_readfirstlane(tid >> 6);   // 0..7
    const float* wrow = wt + half * 8192 + og * 4;
    float a0 = 0.f, a1 = 0.f, a2 = 0.f, a3 = 0.f;
#pragma unroll 8
    for (int c = 0; c < 256; ++c) {
        float xv = xs[c * 64 + wl];
        const float* wp = wrow + c * 32;
        a0 = fmaf(xv, wp[0], a0);
        a1 = fmaf(xv, wp[1], a1);
        a2 = fmaf(xv, wp[2], a2);
        a3 = fmaf(xv, wp[3], a3);
    }
    int o0 = half * 32 + og * 4;
    a0 += b_enc[o0 + 0]; a1 += b_enc[o0 + 1]; a2 += b_enc[o0 + 2]; a3 += b_enc[o0 + 3];
    int cp0 = o0 >> 1;
    xch[((size_t)(b * 32 + cp0)) * 4096 + h * 64 + wl]     = pkh(a0, a1);
    xch[((size_t)(b * 32 + cp0 + 1)) * 4096 + h * 64 + wl] = pkh(a2, a3);
}

// ---------------- B: kp conv (fp16 dot2, s_load weights) + fused softmax -> kerh ----------------
// grid 512: bid = ((b*64 + tile)*4 + g); tile 8x8 px; 256 thr: lane=px, wave=coq
__global__ __launch_bounds__(256) void kp_conv_kernel(const unsigned* __restrict__ xch,
        const unsigned* __restrict__ whr, const float* __restrict__ b_kp,
        unsigned* __restrict__ kerh) {
    __shared__ unsigned xcs[3840];    // [cp32][r10][s pad12], 15.4 KB
    __shared__ float red[6400];       // [coq4][k25][lane64], 25.6 KB
    int bid = blockIdx.x;
    int g = bid & 3;
    int tile = (bid >> 2) & 63;
    int b = bid >> 8;
    int trow = tile >> 3, tcol = tile & 7;
    int tid = threadIdx.x;
    for (int i = 0; i < 15; ++i) {
        int f = i * 256 + tid;
        if (f < 3840) {
            int s = f % 12;
            int r = (f / 12) % 10;
            int cp = f / 120;
            unsigned v = 0;
            int gh = trow * 8 + r - 1, gw = tcol * 8 + s - 1;
            if (s < 10 && gh >= 0 && gh < 64 && gw >= 0 && gw < 64)
                v = xch[((size_t)(b * 32 + cp)) * 4096 + gh * 64 + gw];
            xcs[f] = v;
        }
    }
    __syncthreads();
    int lane = tid & 63;
    int coq = __builtin_amdgcn_readfirstlane(tid >> 6);   // wave-uniform for s_load
    int hy = lane >> 3, hx = lane & 7;
    float acc[25];
#pragma unroll
    for (int k = 0; k < 25; ++k) acc[k] = 0.f;
    const unsigned* wg = whr + g * 8064 + coq * 8 * 252;   // uniform -> scalar pipe
#pragma unroll 1
    for (int ci = 0; ci < 8; ++ci) {
        int cp = coq * 8 + ci;
        const unsigned* xb = xcs + cp * 120 + hy * 12 + hx;
        unsigned xwin[9];
#pragma unroll
        for (int di = 0; di < 3; ++di)
#pragma unroll
            for (int dj = 0; dj < 3; ++dj)
                xwin[di * 3 + dj] = xb[di * 12 + dj];
        const unsigned* wp = wg + ci * 252;
#pragma unroll
        for (int d = 0; d < 9; ++d) {
            h2v xv = u2h(xwin[d]);
#pragma unroll
            for (int k = 0; k < 25; ++k)
                acc[k] = __builtin_amdgcn_fdot2(xv, u2h(wp[d * 28 + k]), acc[k], false);
        }
    }
#pragma unroll
    for (int k = 0; k < 25; ++k) red[coq * 1600 + k * 64 + lane] = acc[k];
    __syncthreads();
    if (coq == 0) {
        float l[25];
#pragma unroll
        for (int k = 0; k < 25; ++k)
            l[k] = red[k * 64 + lane] + red[1600 + k * 64 + lane]
                 + red[3200 + k * 64 + lane] + red[4800 + k * 64 + lane]
                 + b_kp[k * 4 + g];
        float m = l[0];
#pragma unroll
        for (int k = 1; k < 25; ++k) m = fmaxf(m, l[k]);
        float s = 0.f;
#pragma unroll
        for (int k = 0; k < 25; ++k) { l[k] = __expf(l[k] - m); s += l[k]; }
        float inv = 1.f / s;
#pragma unroll
        for (int k = 0; k < 25; ++k) l[k] *= inv;
        int t = trow * 4 + (tcol >> 1);
        int lg = hy * 8 + (tcol & 1) * 4 + (hx >> 1);
        int pxsel = hx & 1;
        unsigned* kb = kerh + ((size_t)((b * 32 + t) * 2 + pxsel)) * 3840 + lg;
#pragma unroll
        for (int i = 0; i < 5; ++i) {
            unsigned u0 = pkh(l[i * 5 + 0], l[i * 5 + 1]);
            unsigned u1 = pkh(l[i * 5 + 2], l[i * 5 + 3]);
            unsigned u2 = pxsel ? pkh(0.f, l[i * 5 + 4]) : pkh(l[i * 5 + 4], 0.f);
            kb[((g * 5 + i) * 3 + 0) * 64] = u0;
            kb[((g * 5 + i) * 3 + 1) * 64] = u1;
            kb[((g * 5 + i) * 3 + 2) * 64] = u2;
        }
    }
}

// ---------------- C: gather, fp16 dot2 ----------------
// grid 1024: bid = (b*32 + t)*16 + cblk16; tile 8x16 px; lane=(hy8,hxp8), px-pair
__global__ __launch_bounds__(256) void gather_kernel(const float* __restrict__ x,
        const unsigned* __restrict__ kerh, float* __restrict__ out) {
    __shared__ unsigned xs[16 * 132];   // [ch][r12][p10 pad11] half2, 8.4 KB
    int bid = blockIdx.x;
    int cblk = bid & 15;
    int t = (bid >> 4) & 31;
    int b = bid >> 9;
    int ty = t >> 2, tx = t & 3;
    int c0 = cblk * 16;
    int tid = threadIdx.x;
    for (int i = 0; i < 8; ++i) {
        int f = i * 256 + tid;
        if (f < 1920) {
            int p = f % 10;
            int r = (f / 10) % 12;
            int ch = f / 120;
            int gh = ty * 8 + r - 2;
            int gw = tx * 16 + 2 * p - 2;
            float v0 = 0.f, v1 = 0.f;
            if (gh >= 0 && gh < 64) {
                const float* xp = x + ((size_t)(b * NC + c0 + ch)) * 4096 + gh * 64;
                if (gw >= 0 && gw < 64) v0 = xp[gw];
                if (gw + 1 >= 0 && gw + 1 < 64) v1 = xp[gw + 1];
            }
            xs[ch * 132 + r * 11 + p] = pkh(v0, v1);
        }
    }
    __syncthreads();
    int lane = tid & 63;
    int wid = tid >> 6;
    int hy = lane >> 3, hxp = lane & 7;
    const unsigned* kb0 = kerh + ((size_t)(b * 32 + t) * 2) * 3840 + lane;
    const unsigned* kb1 = kb0 + 3840;
    unsigned wv[4][5][3];
    float r0[4][4], r1[4][4];
    // ---- phase px0 (w even) ----
#pragma unroll
    for (int g = 0; g < 4; ++g)
#pragma unroll
        for (int i = 0; i < 5; ++i)
#pragma unroll
            for (int j = 0; j < 3; ++j)
                wv[g][i][j] = kb0[((g * 5 + i) * 3 + j) * 64];
#pragma unroll
    for (int ch = 0; ch < 4; ++ch) {
        const unsigned* xb = xs + (wid * 4 + ch) * 132 + hy * 11 + hxp;
        float a0 = 0.f, a1 = 0.f, a2 = 0.f, a3 = 0.f;
#pragma unroll
        for (int i = 0; i < 5; ++i) {
            unsigned A = xb[i * 11], B = xb[i * 11 + 1], C = xb[i * 11 + 2];
            a0 = __builtin_amdgcn_fdot2(u2h(A), u2h(wv[0][i][0]), a0, false);
            a0 = __builtin_amdgcn_fdot2(u2h(B), u2h(wv[0][i][1]), a0, false);
            a0 = __builtin_amdgcn_fdot2(u2h(C), u2h(wv[0][i][2]), a0, false);
            a1 = __builtin_amdgcn_fdot2(u2h(A), u2h(wv[1][i][0]), a1, false);
            a1 = __builtin_amdgcn_fdot2(u2h(B), u2h(wv[1][i][1]), a1, false);
            a1 = __builtin_amdgcn_fdot2(u2h(C), u2h(wv[1][i][2]), a1, false);
            a2 = __builtin_amdgcn_fdot2(u2h(A), u2h(wv[2][i][0]), a2, false);
            a2 = __builtin_amdgcn_fdot2(u2h(B), u2h(wv[2][i][1]), a2, false);
            a2 = __builtin_amdgcn_fdot2(u2h(C), u2h(wv[2][i][2]), a2, false);
            a3 = __builtin_amdgcn_fdot2(u2h(A), u2h(wv[3][i][0]), a3, false);
            a3 = __builtin_amdgcn_fdot2(u2h(B), u2h(wv[3][i][1]), a3, false);
            a3 = __builtin_amdgcn_fdot2(u2h(C), u2h(wv[3][i][2]), a3, false);
        }
        r0[ch][0] = a0; r0[ch][1] = a1; r0[ch][2] = a2; r0[ch][3] = a3;
    }
    // ---- phase px1 (w odd) ----
#pragma unroll
    for (int g = 0; g < 4; ++g)
#pragma unroll
        for (int i = 0; i < 5; ++i)
#pragma unroll
            for (int j = 0; j < 3; ++j)
                wv[g][i][j] = kb1[((g * 5 + i) * 3 + j) * 64];
#pragma unroll
    for (int ch = 0; ch < 4; ++ch) {
        const unsigned* xb = xs + (wid * 4 + ch) * 132 + hy * 11 + hxp;
        float a0 = 0.f, a1 = 0.f, a2 = 0.f, a3 = 0.f;
#pragma unroll
        for (int i = 0; i < 5; ++i) {
            unsigned A = xb[i * 11], B = xb[i * 11 + 1], C = xb[i * 11 + 2];
            unsigned P1 = (A >> 16) | (B << 16);
            unsigned P2 = (B >> 16) | (C << 16);
            a0 = __builtin_amdgcn_fdot2(u2h(P1), u2h(wv[0][i][0]), a0, false);
            a0 = __builtin_amdgcn_fdot2(u2h(P2), u2h(wv[0][i][1]), a0, false);
            a0 = __builtin_amdgcn_fdot2(u2h(C),  u2h(wv[0][i][2]), a0, false);
            a1 = __builtin_amdgcn_fdot2(u2h(P1), u2h(wv[1][i][0]), a1, false);
            a1 = __builtin_amdgcn_fdot2(u2h(P2), u2h(wv[1][i][1]), a1, false);
            a1 = __builtin_amdgcn_fdot2(u2h(C),  u2h(wv[1][i][2]), a1, false);
            a2 = __builtin_amdgcn_fdot2(u2h(P1), u2h(wv[2][i][0]), a2, false);
            a2 = __builtin_amdgcn_fdot2(u2h(P2), u2h(wv[2][i][1]), a2, false);
            a2 = __builtin_amdgcn_fdot2(u2h(C),  u2h(wv[2][i][2]), a2, false);
            a3 = __builtin_amdgcn_fdot2(u2h(P1), u2h(wv[3][i][0]), a3, false);
            a3 = __builtin_amdgcn_fdot2(u2h(P2), u2h(wv[3][i][1]), a3, false);
            a3 = __builtin_amdgcn_fdot2(u2h(C),  u2h(wv[3][i][2]), a3, false);
        }
        r1[ch][0] = a0; r1[ch][1] = a1; r1[ch][2] = a2; r1[ch][3] = a3;
    }
    int oy0 = (ty * 8 + hy) * 2;
    int ox0 = tx * 32 + 4 * hxp;
#pragma unroll
    for (int ch = 0; ch < 4; ++ch) {
        int cc = c0 + wid * 4 + ch;
        float* rb = out + ((size_t)(b * NC + cc) * 128 + oy0) * 128 + ox0;
        *reinterpret_cast<float4*>(rb)       = make_float4(r0[ch][0], r0[ch][1], r1[ch][0], r1[ch][1]);
        *reinterpret_cast<float4*>(rb + 128) = make_float4(r0[ch][2], r0[ch][3], r1[ch][2], r1[ch][3]);
    }
}

extern "C" void kernel_launch(void* const* d_in, const int* in_sizes, int n_in,
                              void* d_out, int out_size, void* d_ws, size_t ws_size,
                              hipStream_t stream) {
    const float* x     = (const float*)d_in[0];
    const float* w_enc = (const float*)d_in[1];
    const float* b_enc = (const float*)d_in[2];
    const float* w_kp  = (const float*)d_in[3];
    const float* b_kp  = (const float*)d_in[4];
    float* out = (float*)d_out;

    float* wt = (float*)d_ws;                    // 16384 f32
    unsigned* whr  = (unsigned*)(wt + 16384);    // 32256 u32
    unsigned* xch  = whr + 32256;                // 2*32*4096 = 262144 u32
    unsigned* kerh = xch + 262144;               // 2*32*2*3840 = 491520 u32

    prep_weights<<<190, 256, 0, stream>>>(w_kp, w_enc, whr, wt);
    encoder_kernel<<<256, 512, 0, stream>>>(x, wt, b_enc, xch);
    kp_conv_kernel<<<512, 256, 0, stream>>>(xch, whr, b_kp, kerh);
    gather_kernel<<<1024, 256, 0, stream>>>(x, kerh, out);
}

// Round 7
// 55.773 us; speedup vs baseline: 1.2402x; 1.2402x over previous
//
#include <hip/hip_runtime.h>

// CARAFE upsample: B=2, C=256, H=W=64, S=2, K=5, COMP=64, KP=100
// encoder (1x1, s_load w_enc, fp16-pair out, + whr build) ->
// kp conv (3x3 fp16 dot2, s_load weights, fused 4-wave softmax) -> gather (fp16 dot2)

#define NB 2
#define NC 256

typedef _Float16 h2v __attribute__((ext_vector_type(2)));
typedef __fp16 f16x2 __attribute__((ext_vector_type(2)));
union U32H2 { unsigned u; h2v h; f16x2 f; };
static __device__ __forceinline__ h2v u2h(unsigned u) { U32H2 t; t.u = u; return t.h; }
static __device__ __forceinline__ unsigned pkh(float a, float b) {
    U32H2 t; t.f = __builtin_amdgcn_cvt_pkrtz(a, b); return t.u;
}

// ---------------- A: encoder -> xch[b][cp32][px4096] fp16 pairs; + whr build ----------------
// grid 256: bid -> b=bid>>7, hi=(bid>>4)&7, half=(bid>>3)&1, lo=bid&7, h=hi*8+lo.
// Blocks {k, k+8} = two halves of same (b,h) row -> same XCD (bid%8 equal) -> x row
// fetched once per XCD L2. 512 thr = 8 waves; wave og -> 4 outputs, w via s_load.
__global__ __launch_bounds__(512) void encoder_kernel(const float* __restrict__ x,
        const float* __restrict__ w_enc, const float* __restrict__ b_enc,
        const float* __restrict__ w_kp, unsigned* __restrict__ xch,
        unsigned* __restrict__ whr) {
    __shared__ float xs[256 * 64];   // 64 KB
    int bid = blockIdx.x;
    int b = bid >> 7;
    int hi = (bid >> 4) & 7;
    int half = (bid >> 3) & 1;
    int lo = bid & 7;
    int h = hi * 8 + lo;
    int tid = threadIdx.x;
    // whr[g][cp32][d9][k2 pad28] fp16-pairs, built by first 63 blocks
    if (bid < 63) {
        int idx = bid * 512 + tid;
        if (idx < 32256) {
            int k = idx % 28;
            int d = (idx / 28) % 9;
            int cp = (idx / 252) % 32;
            int g = idx / 8064;
            unsigned val = 0;
            if (k < 25) {
                float a = w_kp[((size_t)(k * 4 + g) * 64 + 2 * cp) * 9 + d];
                float bb = w_kp[((size_t)(k * 4 + g) * 64 + 2 * cp + 1) * 9 + d];
                val = pkh(a, bb);
            }
            whr[idx] = val;
        }
    }
    const float* xb = x + ((size_t)(b * NC)) * 4096 + h * 64;
    for (int i = 0; i < 8; ++i) {
        int f = i * 512 + tid;          // float4 index: 4096 total
        int c = f >> 4, w4 = f & 15;
        *reinterpret_cast<float4*>(xs + c * 64 + w4 * 4) =
            *reinterpret_cast<const float4*>(xb + (size_t)c * 4096 + w4 * 4);
    }
    __syncthreads();
    int wl = tid & 63;
    int og = __builtin_amdgcn_readfirstlane(tid >> 6);   // 0..7
    const float* w0 = w_enc + (size_t)(half * 32 + og * 4) * 256;  // 4 rows, stride 256
    float a0 = 0.f, a1 = 0.f, a2 = 0.f, a3 = 0.f;
#pragma unroll 8
    for (int c = 0; c < 256; ++c) {
        float xv = xs[c * 64 + wl];
        a0 = fmaf(xv, w0[c], a0);
        a1 = fmaf(xv, w0[256 + c], a1);
        a2 = fmaf(xv, w0[512 + c], a2);
        a3 = fmaf(xv, w0[768 + c], a3);
    }
    int o0 = half * 32 + og * 4;
    a0 += b_enc[o0 + 0]; a1 += b_enc[o0 + 1]; a2 += b_enc[o0 + 2]; a3 += b_enc[o0 + 3];
    int cp0 = o0 >> 1;
    xch[((size_t)(b * 32 + cp0)) * 4096 + h * 64 + wl]     = pkh(a0, a1);
    xch[((size_t)(b * 32 + cp0 + 1)) * 4096 + h * 64 + wl] = pkh(a2, a3);
}

// ---------------- B: kp conv (fp16 dot2, s_load weights) + fused 4-wave softmax ----------------
// grid 512: bid = ((b*64 + tile)*4 + g); tile 8x8 px; 256 thr: lane=px, wave=coq
__global__ __launch_bounds__(256) void kp_conv_kernel(const unsigned* __restrict__ xch,
        const unsigned* __restrict__ whr, const float* __restrict__ b_kp,
        unsigned* __restrict__ kerh) {
    __shared__ unsigned xcs[3840];    // [cp32][r10][s pad12], 15.4 KB
    __shared__ float red[6400];       // [coq4][k25][px64], 25.6 KB
    int bid = blockIdx.x;
    int g = bid & 3;
    int tile = (bid >> 2) & 63;
    int b = bid >> 8;
    int trow = tile >> 3, tcol = tile & 7;
    int tid = threadIdx.x;
    for (int i = 0; i < 15; ++i) {
        int f = i * 256 + tid;
        if (f < 3840) {
            int s = f % 12;
            int r = (f / 12) % 10;
            int cp = f / 120;
            unsigned v = 0;
            int gh = trow * 8 + r - 1, gw = tcol * 8 + s - 1;
            if (s < 10 && gh >= 0 && gh < 64 && gw >= 0 && gw < 64)
                v = xch[((size_t)(b * 32 + cp)) * 4096 + gh * 64 + gw];
            xcs[f] = v;
        }
    }
    __syncthreads();
    int lane = tid & 63;
    int coq = __builtin_amdgcn_readfirstlane(tid >> 6);   // wave-uniform for s_load
    int hy = lane >> 3, hx = lane & 7;
    float acc[25];
#pragma unroll
    for (int k = 0; k < 25; ++k) acc[k] = 0.f;
    const unsigned* wg = whr + g * 8064 + coq * 8 * 252;   // uniform -> scalar pipe
#pragma unroll 1
    for (int ci = 0; ci < 8; ++ci) {
        int cp = coq * 8 + ci;
        const unsigned* xb = xcs + cp * 120 + hy * 12 + hx;
        unsigned xwin[9];
#pragma unroll
        for (int di = 0; di < 3; ++di)
#pragma unroll
            for (int dj = 0; dj < 3; ++dj)
                xwin[di * 3 + dj] = xb[di * 12 + dj];
        const unsigned* wp = wg + ci * 252;
#pragma unroll
        for (int d = 0; d < 9; ++d) {
            h2v xv = u2h(xwin[d]);
#pragma unroll
            for (int k = 0; k < 25; ++k)
                acc[k] = __builtin_amdgcn_fdot2(xv, u2h(wp[d * 28 + k]), acc[k], false);
        }
    }
#pragma unroll
    for (int k = 0; k < 25; ++k) red[coq * 1600 + k * 64 + lane] = acc[k];
    __syncthreads();
    // 4-wave softmax: wave w handles px w*16..w*16+15; lanes 16-63 duplicate (LDS broadcast)
    {
        int px = coq * 16 + (lane & 15);
        float l[25];
#pragma unroll
        for (int k = 0; k < 25; ++k)
            l[k] = red[k * 64 + px] + red[1600 + k * 64 + px]
                 + red[3200 + k * 64 + px] + red[4800 + k * 64 + px]
                 + b_kp[k * 4 + g];
        float m = l[0];
#pragma unroll
        for (int k = 1; k < 25; ++k) m = fmaxf(m, l[k]);
        float s = 0.f;
#pragma unroll
        for (int k = 0; k < 25; ++k) { l[k] = __expf(l[k] - m); s += l[k]; }
        float inv = 1.f / s;
#pragma unroll
        for (int k = 0; k < 25; ++k) l[k] *= inv;
        int phy = px >> 3, phx = px & 7;
        int t = trow * 4 + (tcol >> 1);
        int lg = phy * 8 + (tcol & 1) * 4 + (phx >> 1);
        int pxsel = phx & 1;
        unsigned* kb = kerh + ((size_t)((b * 32 + t) * 2 + pxsel)) * 3840 + lg;
        if ((lane >> 4) == 0) {
#pragma unroll
            for (int i = 0; i < 5; ++i) {
                unsigned u0 = pkh(l[i * 5 + 0], l[i * 5 + 1]);
                unsigned u1 = pkh(l[i * 5 + 2], l[i * 5 + 3]);
                unsigned u2 = pxsel ? pkh(0.f, l[i * 5 + 4]) : pkh(l[i * 5 + 4], 0.f);
                kb[((g * 5 + i) * 3 + 0) * 64] = u0;
                kb[((g * 5 + i) * 3 + 1) * 64] = u1;
                kb[((g * 5 + i) * 3 + 2) * 64] = u2;
            }
        }
    }
}

// ---------------- C: gather, fp16 dot2, 32 ch/block ----------------
// grid 512: bid = (b*32 + t)*8 + cblk8; tile 8x16 px; lane=(hy8,hxp8), px-pair
__global__ __launch_bounds__(256) void gather_kernel(const float* __restrict__ x,
        const unsigned* __restrict__ kerh, float* __restrict__ out) {
    __shared__ unsigned xs[32 * 132];   // [ch][r12][p10 pad11] half2, 16.9 KB
    int bid = blockIdx.x;
    int cblk = bid & 7;
    int t = (bid >> 3) & 31;
    int b = bid >> 8;
    int ty = t >> 2, tx = t & 3;
    int c0 = cblk * 32;
    int tid = threadIdx.x;
    for (int i = 0; i < 15; ++i) {
        int f = i * 256 + tid;
        if (f < 3840) {
            int p = f % 10;
            int r = (f / 10) % 12;
            int ch = f / 120;
            int gh = ty * 8 + r - 2;
            int gw = tx * 16 + 2 * p - 2;
            float v0 = 0.f, v1 = 0.f;
            if (gh >= 0 && gh < 64) {
                const float* xp = x + ((size_t)(b * NC + c0 + ch)) * 4096 + gh * 64;
                if (gw >= 0 && gw < 64) v0 = xp[gw];
                if (gw + 1 >= 0 && gw + 1 < 64) v1 = xp[gw + 1];
            }
            xs[ch * 132 + r * 11 + p] = pkh(v0, v1);
        }
    }
    __syncthreads();
    int lane = tid & 63;
    int wid = tid >> 6;
    int hy = lane >> 3, hxp = lane & 7;
    const unsigned* kb0 = kerh + ((size_t)(b * 32 + t) * 2) * 3840 + lane;
    const unsigned* kb1 = kb0 + 3840;
    unsigned wv[4][5][3];
    float r0[8][4], r1[8][4];
    // ---- phase px0 (w even) ----
#pragma unroll
    for (int g = 0; g < 4; ++g)
#pragma unroll
        for (int i = 0; i < 5; ++i)
#pragma unroll
            for (int j = 0; j < 3; ++j)
                wv[g][i][j] = kb0[((g * 5 + i) * 3 + j) * 64];
#pragma unroll
    for (int ch = 0; ch < 8; ++ch) {
        const unsigned* xb = xs + (wid * 8 + ch) * 132 + hy * 11 + hxp;
        float a0 = 0.f, a1 = 0.f, a2 = 0.f, a3 = 0.f;
#pragma unroll
        for (int i = 0; i < 5; ++i) {
            unsigned A = xb[i * 11], B = xb[i * 11 + 1], C = xb[i * 11 + 2];
            a0 = __builtin_amdgcn_fdot2(u2h(A), u2h(wv[0][i][0]), a0, false);
            a0 = __builtin_amdgcn_fdot2(u2h(B), u2h(wv[0][i][1]), a0, false);
            a0 = __builtin_amdgcn_fdot2(u2h(C), u2h(wv[0][i][2]), a0, false);
            a1 = __builtin_amdgcn_fdot2(u2h(A), u2h(wv[1][i][0]), a1, false);
            a1 = __builtin_amdgcn_fdot2(u2h(B), u2h(wv[1][i][1]), a1, false);
            a1 = __builtin_amdgcn_fdot2(u2h(C), u2h(wv[1][i][2]), a1, false);
            a2 = __builtin_amdgcn_fdot2(u2h(A), u2h(wv[2][i][0]), a2, false);
            a2 = __builtin_amdgcn_fdot2(u2h(B), u2h(wv[2][i][1]), a2, false);
            a2 = __builtin_amdgcn_fdot2(u2h(C), u2h(wv[2][i][2]), a2, false);
            a3 = __builtin_amdgcn_fdot2(u2h(A), u2h(wv[3][i][0]), a3, false);
            a3 = __builtin_amdgcn_fdot2(u2h(B), u2h(wv[3][i][1]), a3, false);
            a3 = __builtin_amdgcn_fdot2(u2h(C), u2h(wv[3][i][2]), a3, false);
        }
        r0[ch][0] = a0; r0[ch][1] = a1; r0[ch][2] = a2; r0[ch][3] = a3;
    }
    // ---- phase px1 (w odd) ----
#pragma unroll
    for (int g = 0; g < 4; ++g)
#pragma unroll
        for (int i = 0; i < 5; ++i)
#pragma unroll
            for (int j = 0; j < 3; ++j)
                wv[g][i][j] = kb1[((g * 5 + i) * 3 + j) * 64];
#pragma unroll
    for (int ch = 0; ch < 8; ++ch) {
        const unsigned* xb = xs + (wid * 8 + ch) * 132 + hy * 11 + hxp;
        float a0 = 0.f, a1 = 0.f, a2 = 0.f, a3 = 0.f;
#pragma unroll
        for (int i = 0; i < 5; ++i) {
            unsigned A = xb[i * 11], B = xb[i * 11 + 1], C = xb[i * 11 + 2];
            unsigned P1 = (A >> 16) | (B << 16);
            unsigned P2 = (B >> 16) | (C << 16);
            a0 = __builtin_amdgcn_fdot2(u2h(P1), u2h(wv[0][i][0]), a0, false);
            a0 = __builtin_amdgcn_fdot2(u2h(P2), u2h(wv[0][i][1]), a0, false);
            a0 = __builtin_amdgcn_fdot2(u2h(C),  u2h(wv[0][i][2]), a0, false);
            a1 = __builtin_amdgcn_fdot2(u2h(P1), u2h(wv[1][i][0]), a1, false);
            a1 = __builtin_amdgcn_fdot2(u2h(P2), u2h(wv[1][i][1]), a1, false);
            a1 = __builtin_amdgcn_fdot2(u2h(C),  u2h(wv[1][i][2]), a1, false);
            a2 = __builtin_amdgcn_fdot2(u2h(P1), u2h(wv[2][i][0]), a2, false);
            a2 = __builtin_amdgcn_fdot2(u2h(P2), u2h(wv[2][i][1]), a2, false);
            a2 = __builtin_amdgcn_fdot2(u2h(C),  u2h(wv[2][i][2]), a2, false);
            a3 = __builtin_amdgcn_fdot2(u2h(P1), u2h(wv[3][i][0]), a3, false);
            a3 = __builtin_amdgcn_fdot2(u2h(P2), u2h(wv[3][i][1]), a3, false);
            a3 = __builtin_amdgcn_fdot2(u2h(C),  u2h(wv[3][i][2]), a3, false);
        }
        r1[ch][0] = a0; r1[ch][1] = a1; r1[ch][2] = a2; r1[ch][3] = a3;
    }
    int oy0 = (ty * 8 + hy) * 2;
    int ox0 = tx * 32 + 4 * hxp;
#pragma unroll
    for (int ch = 0; ch < 8; ++ch) {
        int cc = c0 + wid * 8 + ch;
        float* rb = out + ((size_t)(b * NC + cc) * 128 + oy0) * 128 + ox0;
        *reinterpret_cast<float4*>(rb)       = make_float4(r0[ch][0], r0[ch][1], r1[ch][0], r1[ch][1]);
        *reinterpret_cast<float4*>(rb + 128) = make_float4(r0[ch][2], r0[ch][3], r1[ch][2], r1[ch][3]);
    }
}

extern "C" void kernel_launch(void* const* d_in, const int* in_sizes, int n_in,
                              void* d_out, int out_size, void* d_ws, size_t ws_size,
                              hipStream_t stream) {
    const float* x     = (const float*)d_in[0];
    const float* w_enc = (const float*)d_in[1];
    const float* b_enc = (const float*)d_in[2];
    const float* w_kp  = (const float*)d_in[3];
    const float* b_kp  = (const float*)d_in[4];
    float* out = (float*)d_out;

    unsigned* whr  = (unsigned*)d_ws;            // 32256 u32
    unsigned* xch  = whr + 32256;                // 2*32*4096 = 262144 u32
    unsigned* kerh = xch + 262144;               // 2*32*2*3840 = 491520 u32

    encoder_kernel<<<256, 512, 0, stream>>>(x, w_enc, b_enc, w_kp, xch, whr);
    kp_conv_kernel<<<512, 256, 0, stream>>>(xch, whr, b_kp, kerh);
    gather_kernel<<<512, 256, 0, stream>>>(x, kerh, out);
}